// Round 11
// baseline (247.784 us; speedup 1.0000x reference)
//
// v11: build-side occupancy restoration. Round-10's perm-staged ordered writes
// kept, but the redundant vals[] LDS payload dropped (re-read from L1/L2-hot
// global windows instead): k_bscatter2 57->25 KB LDS (2->6 blocks/CU),
// k_bsort 48->18 KB (3->8 blocks/CU). k_scan3 deleted from the main path
// (+bsum fold-up moved into consumers). k_node1/k_node2out byte-identical.
#include <hip/hip_runtime.h>
#include <hip/hip_fp16.h>

#define HID 32
#define LEAKY 0.01f
#define SE3NORM 0.17677669529663687f   // 1/sqrt(32)
#define SCAN_TILE 1024                 // elements per scan block (256 thr x 4)
#define NBK 128                        // nodes per fine bucket
#define GA 320                         // pass-A blocks (chunk 7813 <= CHCAP)
#define CHCAP 8192                     // max staged elements (uint16 perm)
#define NPB2 64                        // nodes per block in k_node2out (512 threads)

// ======================= two-level bucket CSR build (no global atomics) =======================

// pass A1: per-block LDS histogram of coarse bucket (dst>>7); bh[b*GA + g] = count
__global__ void k_bhist(const int* __restrict__ ei, int* __restrict__ bh,
                        int E, int B1, int chunk) {
    extern __shared__ int lh[];                 // B1 ints
    int g = blockIdx.x;
    for (int i = threadIdx.x; i < B1; i += 256) lh[i] = 0;
    __syncthreads();
    int beg = g * chunk, end = min(E, beg + chunk);
    for (int e = beg + (int)threadIdx.x; e < end; e += 256)
        atomicAdd(&lh[ei[E + e] >> 7], 1);
    __syncthreads();
    for (int b = threadIdx.x; b < B1; b += 256) bh[b * GA + g] = lh[b];
}

// scan pass 1: per-tile exclusive scan IN PLACE + tile sums
__global__ void k_scan1(int* __restrict__ data, int* __restrict__ bsum, int M) {
    __shared__ int lds[256];
    int t = threadIdx.x;
    int base = blockIdx.x * SCAN_TILE + t * 4;
    int v0 = (base + 0 < M) ? data[base + 0] : 0;
    int v1 = (base + 1 < M) ? data[base + 1] : 0;
    int v2 = (base + 2 < M) ? data[base + 2] : 0;
    int v3 = (base + 3 < M) ? data[base + 3] : 0;
    int s = v0 + v1 + v2 + v3;
    lds[t] = s;
    __syncthreads();
    for (int off = 1; off < 256; off <<= 1) {
        int x = (t >= off) ? lds[t - off] : 0;
        __syncthreads();
        lds[t] += x;
        __syncthreads();
    }
    int ex = lds[t] - s;
    if (base + 0 < M) data[base + 0] = ex;
    if (base + 1 < M) data[base + 1] = ex + v0;
    if (base + 2 < M) data[base + 2] = ex + v0 + v1;
    if (base + 3 < M) data[base + 3] = ex + v0 + v1 + v2;
    if (t == 255) bsum[blockIdx.x] = lds[255];
}

// scan pass 2: exclusive scan of tile sums (single block, B<=256)
__global__ void k_scan2(int* __restrict__ bsum, int B) {
    __shared__ int lds[256];
    int t = threadIdx.x;
    int v = (t < B) ? bsum[t] : 0;
    lds[t] = v;
    __syncthreads();
    for (int off = 1; off < 256; off <<= 1) {
        int x = (t >= off) ? lds[t - off] : 0;
        __syncthreads();
        lds[t] += x;
        __syncthreads();
    }
    if (t < B) bsum[t] = lds[t] - v;
}

// scan pass 3: add tile prefix in place (FALLBACK PATH ONLY in v11)
__global__ void k_scan3(int* __restrict__ data, const int* __restrict__ bsum,
                        int* __restrict__ cursor, int M, int N) {
    int i = blockIdx.x * blockDim.x + threadIdx.x;
    if (i >= M) return;
    int off = data[i] + bsum[i / SCAN_TILE];
    data[i] = off;
    if (cursor && i < N) cursor[i] = off;
}

// pass A3 v3: perm-staged ORDERED scatter, no vals staging (25 KB LDS -> 6 blk/CU).
// bh holds per-tile partial scans; +bsum[idx>>10] applied here (k_scan3 deleted).
// LDS: cur[B1] | hist[B1] | base[B1] | perm[CHCAP u16]
__global__ __launch_bounds__(256, 1) void k_bscatter2(
        const int* __restrict__ ei, const int* __restrict__ bh,
        const int* __restrict__ bsum,
        int* __restrict__ bucketed, int E, int B1, int chunk) {
    extern __shared__ int lh[];
    int* cur  = lh;
    int* hist = lh + B1;
    int* base = lh + 2 * B1;
    unsigned short* perm = (unsigned short*)(lh + 3 * B1);
    __shared__ int scanbuf[256];
    const int g = blockIdx.x;
    const int t = threadIdx.x;
    const int beg = g * chunk;
    const int end = min(E, beg + chunk);
    const int sz = end - beg;

    for (int b = t; b < B1; b += 256) {
        int idx = b * GA + g;
        cur[b] = bh[idx] + bsum[idx >> 10];      // SCAN_TILE == 1024
        hist[b] = 0;
    }
    __syncthreads();
    // pass A: coalesced dst read -> count only
    for (int i = t; i < sz; i += 256)
        atomicAdd(&hist[ei[E + beg + i] >> 7], 1);
    __syncthreads();
    // exclusive scan of hist (B1 <= 1024): 4 buckets/thread serial + 256-scan
    {
        int k0 = t * 4;
        int c0 = (k0 + 0 < B1) ? hist[k0 + 0] : 0;
        int c1 = (k0 + 1 < B1) ? hist[k0 + 1] : 0;
        int c2 = (k0 + 2 < B1) ? hist[k0 + 2] : 0;
        int c3 = (k0 + 3 < B1) ? hist[k0 + 3] : 0;
        int ssum = c0 + c1 + c2 + c3;
        scanbuf[t] = ssum;
        __syncthreads();
        for (int off = 1; off < 256; off <<= 1) {
            int x = (t >= off) ? scanbuf[t - off] : 0;
            __syncthreads();
            scanbuf[t] += x;
            __syncthreads();
        }
        int ex = scanbuf[t] - ssum;
        if (k0 + 0 < B1) { base[k0 + 0] = ex; ex += c0; }
        if (k0 + 1 < B1) { base[k0 + 1] = ex; ex += c1; }
        if (k0 + 2 < B1) { base[k0 + 2] = ex; ex += c2; }
        if (k0 + 3 < B1) { base[k0 + 3] = ex; ex += c3; }
    }
    __syncthreads();
    for (int b = t; b < B1; b += 256) hist[b] = base[b];  // cursor
    __syncthreads();
    // pass B: coalesced dst re-read (L2-hot 31 KB window) -> permutation
    for (int i = t; i < sz; i += 256) {
        int bid = ei[E + beg + i] >> 7;
        int p = atomicAdd(&hist[bid], 1);
        perm[p] = (unsigned short)i;
    }
    __syncthreads();
    // output: linear over output positions -> ordered global writes;
    // d/s re-read via perm are random within L1/L2-hot 31 KB windows.
    for (int p = t; p < sz; p += 256) {
        int i = perm[p];
        int d = ei[E + beg + i];
        int s = ei[beg + i];
        int bid = d >> 7;
        bucketed[cur[bid] + (p - base[bid])] = s | ((d & (NBK - 1)) << 24);
    }
}

// pass B v3: counting sort, perm-only LDS (18 KB -> 8 blk/CU), ordered writes.
// bh partial scans + bsum applied here. Oversized buckets: unordered fallback.
__global__ __launch_bounds__(256, 1) void k_bsort(
        const int* __restrict__ bh, const int* __restrict__ bsum,
        const int* __restrict__ bucketed,
        int* __restrict__ sorted_src, int* __restrict__ offsets,
        int E, int N, int B1) {
    __shared__ int hist[NBK], sc[NBK], base[NBK];
    __shared__ unsigned short perm[CHCAP];         // 16 KB
    int b = blockIdx.x;
    int t = threadIdx.x;
    int i0 = b * GA;
    int bs = bh[i0] + bsum[i0 >> 10];
    int be;
    if (b == B1 - 1) be = E;
    else { int i1 = (b + 1) * GA; be = bh[i1] + bsum[i1 >> 10]; }
    int sz = be - bs;
    if (t < NBK) hist[t] = 0;
    __syncthreads();

    if (sz <= CHCAP) {
        // count (coalesced read; bucket window ~12.5 KB stays L1/L2-hot)
        for (int i = t; i < sz; i += 256)
            atomicAdd(&hist[bucketed[bs + i] >> 24], 1);
        __syncthreads();
        int v = (t < NBK) ? hist[t] : 0;
        if (t < NBK) sc[t] = v;
        __syncthreads();
        for (int off = 1; off < NBK; off <<= 1) {
            int x = (t < NBK && t >= off) ? sc[t - off] : 0;
            __syncthreads();
            if (t < NBK) sc[t] += x;
            __syncthreads();
        }
        if (t < NBK) base[t] = sc[t] - v;           // exclusive
        __syncthreads();
        if (t < NBK) hist[t] = base[t];             // cursor
        __syncthreads();
        // coalesced re-read -> permutation
        for (int i = t; i < sz; i += 256) {
            int p = atomicAdd(&hist[bucketed[bs + i] >> 24], 1);
            perm[p] = (unsigned short)i;
        }
        __syncthreads();
        // ordered write; random re-read within L1-hot bucket window
        for (int p = t; p < sz; p += 256)
            sorted_src[bs + p] = bucketed[bs + perm[p]] & 0x00FFFFFF;
    } else {
        // fallback: two reads, unordered writes
        for (int e = bs + t; e < be; e += 256)
            atomicAdd(&hist[bucketed[e] >> 24], 1);
        __syncthreads();
        int v = (t < NBK) ? hist[t] : 0;
        if (t < NBK) sc[t] = v;
        __syncthreads();
        for (int off = 1; off < NBK; off <<= 1) {
            int x = (t < NBK && t >= off) ? sc[t - off] : 0;
            __syncthreads();
            if (t < NBK) sc[t] += x;
            __syncthreads();
        }
        if (t < NBK) base[t] = sc[t] - v;
        __syncthreads();
        if (t < NBK) hist[t] = base[t];
        __syncthreads();
        for (int e = bs + t; e < be; e += 256) {
            int pv = bucketed[e];
            int p = atomicAdd(&hist[pv >> 24], 1);
            sorted_src[bs + p] = pv & 0x00FFFFFF;
        }
    }
    int node = b * NBK + t;
    if (t < NBK && node < N) offsets[node] = bs + base[t];
    if (b == B1 - 1 && t == 0) offsets[N] = E;
}

// ======================= fallback CSR build (global atomics, R4 path) =======================
__global__ void k_hist_rank(const int* __restrict__ ei, int* __restrict__ hist,
                            int* __restrict__ rank, int E) {
    int base = (blockIdx.x * blockDim.x + threadIdx.x) * 4;
#pragma unroll
    for (int u = 0; u < 4; u++) {
        int e = base + u;
        if (e < E) rank[e] = atomicAdd(&hist[ei[E + e]], 1);
    }
}
__global__ void k_hist(const int* __restrict__ ei, int* __restrict__ hist, int E) {
    int base = (blockIdx.x * blockDim.x + threadIdx.x) * 4;
#pragma unroll
    for (int u = 0; u < 4; u++) {
        int e = base + u;
        if (e < E) atomicAdd(&hist[ei[E + e]], 1);
    }
}
__global__ void k_scatter_rank(const int* __restrict__ ei, const int* __restrict__ offsets,
                               const int* __restrict__ rank, int* __restrict__ sorted_src, int E) {
    int base = (blockIdx.x * blockDim.x + threadIdx.x) * 4;
#pragma unroll
    for (int u = 0; u < 4; u++) {
        int e = base + u;
        if (e < E) sorted_src[offsets[ei[E + e]] + rank[e]] = ei[e];
    }
}
__global__ void k_scatter_atomic(const int* __restrict__ ei, int* __restrict__ cursor,
                                 int* __restrict__ sorted_src, int E) {
    int base = (blockIdx.x * blockDim.x + threadIdx.x) * 4;
#pragma unroll
    for (int u = 0; u < 4; u++) {
        int e = base + u;
        if (e < E) {
            int p = atomicAdd(&cursor[ei[E + e]], 1);
            sorted_src[p] = ei[e];
        }
    }
}

// ======================= node-level fused kernels =======================
// layer 1 (round-9 verified): 8 thr/node, shfl-reduced partials, b128 weight reads.
__global__ __launch_bounds__(256, 1) void k_node1(
                        const int* __restrict__ offsets, const int* __restrict__ sorted_src,
                        const float* __restrict__ pos,
                        const float* __restrict__ Wl1, const float* __restrict__ bl1,
                        const float* __restrict__ Wr1, const float* __restrict__ Wse1,
                        __half* __restrict__ h1, int N) {
    __shared__ float sWl1[2 * HID], sWr1[2 * HID], sbl1[HID], sWse1[HID * HID];
    __shared__ float sH[32][HID + 4];
    for (int i = threadIdx.x; i < 2 * HID; i += blockDim.x) { sWl1[i] = Wl1[i]; sWr1[i] = Wr1[i]; }
    for (int i = threadIdx.x; i < HID; i += blockDim.x) sbl1[i] = bl1[i];
    for (int i = threadIdx.x; i < HID * HID; i += blockDim.x) sWse1[i] = Wse1[i];
    __syncthreads();

    const int lt = threadIdx.x;
    const int nodeL = lt >> 3;
    const int t = lt & 7;
    const int node = blockIdx.x * 32 + nodeL;
    const bool live = node < N;

    float a0 = 0.f, a1 = 0.f;
    if (live) {
        int beg = offsets[node], end = offsets[node + 1];
        for (int e = beg + t; e < end; e += 8) {
            int s = sorted_src[e];
            a0 += pos[s * 3];
            a1 += pos[s * 3 + 1];
        }
    }
    a0 += __shfl_xor(a0, 1); a1 += __shfl_xor(a1, 1);
    a0 += __shfl_xor(a0, 2); a1 += __shfl_xor(a1, 2);
    a0 += __shfl_xor(a0, 4); a1 += __shfl_xor(a1, 4);

    if (live) {
        float x0 = pos[3 * node], x1 = pos[3 * node + 1];
#pragma unroll
        for (int jj = 0; jj < 4; jj++) {
            int k = t * 4 + jj;
            float v = a0 * sWl1[k] + a1 * sWl1[HID + k] + sbl1[k] + x0 * sWr1[k] + x1 * sWr1[HID + k];
            sH[nodeL][k] = v > 0.f ? v : LEAKY * v;
        }
    }
    __syncthreads();

    if (live) {
        float4 acc = make_float4(0.f, 0.f, 0.f, 0.f);
#pragma unroll 8
        for (int k = 0; k < HID; k++) {
            float hk = sH[nodeL][k];
            float4 w = *(const float4*)&sWse1[k * HID + t * 4];
            acc.x += hk * w.x; acc.y += hk * w.y;
            acc.z += hk * w.z; acc.w += hk * w.w;
        }
        union Pack4 { __half h[4]; float2 v; } p;
        p.h[0] = __float2half(acc.x * SE3NORM);
        p.h[1] = __float2half(acc.y * SE3NORM);
        p.h[2] = __float2half(acc.z * SE3NORM);
        p.h[3] = __float2half(acc.w * SE3NORM);
        *(float2*)&h1[(size_t)node * HID + t * 4] = p.v;
    }
}

// accumulate an 8-byte h1 fragment (4 halves in a float2)
__device__ __forceinline__ void acc_h1frag(float2 r, float4& acc) {
    __half2 p01 = __builtin_bit_cast(__half2, r.x);
    __half2 p23 = __builtin_bit_cast(__half2, r.y);
    acc.x += __low2float(p01); acc.y += __high2float(p01);
    acc.z += __low2float(p23); acc.w += __high2float(p23);
}

// layer 2 + head (round-6/9 verified 74 us, bytes/BW-bound). Untouched.
__global__ __launch_bounds__(512, 1) void k_node2out(
                           const int* __restrict__ offsets, const int* __restrict__ sorted_src,
                           const __half* __restrict__ h1,
                           const float* __restrict__ Wl2, const float* __restrict__ bl2,
                           const float* __restrict__ Wr2, const float* __restrict__ Wse2,
                           const float* __restrict__ W3, const float* __restrict__ b3,
                           const float* __restrict__ W4, const float* __restrict__ b4,
                           const float* __restrict__ alpha_p,
                           float* __restrict__ out, int N) {
    __shared__ float sWl2[HID * HID], sWr2[HID * HID], sWse2[HID * HID], sW3[HID * HID];
    __shared__ float sbl2[HID], sb3[HID], sW4[HID];
    __shared__ float sb4, salpha;
    __shared__ float sA[NPB2][HID + 4], sB[NPB2][HID + 4];
    for (int i = threadIdx.x; i < HID * HID; i += blockDim.x) {
        sWl2[i] = Wl2[i]; sWr2[i] = Wr2[i]; sWse2[i] = Wse2[i]; sW3[i] = W3[i];
    }
    for (int i = threadIdx.x; i < HID; i += blockDim.x) { sbl2[i] = bl2[i]; sb3[i] = b3[i]; sW4[i] = W4[i]; }
    if (threadIdx.x == 0) { sb4 = b4[0]; salpha = alpha_p[0]; }
    __syncthreads();

    const int lt = threadIdx.x;
    const int nodeL = lt >> 3;       // 0..63
    const int t = lt & 7;
    const int node = blockIdx.x * NPB2 + nodeL;
    const bool live = node < N;

    if (live) {
        float2 ro = *(const float2*)&h1[(size_t)node * HID + t * 4];

        int beg = offsets[node], end = offsets[node + 1];
        float4 acc = make_float4(0.f, 0.f, 0.f, 0.f);
        int e = beg;
        for (; e + 8 <= end; e += 8) {
            int s0 = __builtin_nontemporal_load(&sorted_src[e + 0]);
            int s1 = __builtin_nontemporal_load(&sorted_src[e + 1]);
            int s2 = __builtin_nontemporal_load(&sorted_src[e + 2]);
            int s3 = __builtin_nontemporal_load(&sorted_src[e + 3]);
            int s4 = __builtin_nontemporal_load(&sorted_src[e + 4]);
            int s5 = __builtin_nontemporal_load(&sorted_src[e + 5]);
            int s6 = __builtin_nontemporal_load(&sorted_src[e + 6]);
            int s7 = __builtin_nontemporal_load(&sorted_src[e + 7]);
            float2 r0 = *(const float2*)&h1[(size_t)s0 * HID + t * 4];
            float2 r1 = *(const float2*)&h1[(size_t)s1 * HID + t * 4];
            float2 r2 = *(const float2*)&h1[(size_t)s2 * HID + t * 4];
            float2 r3 = *(const float2*)&h1[(size_t)s3 * HID + t * 4];
            float2 r4 = *(const float2*)&h1[(size_t)s4 * HID + t * 4];
            float2 r5 = *(const float2*)&h1[(size_t)s5 * HID + t * 4];
            float2 r6 = *(const float2*)&h1[(size_t)s6 * HID + t * 4];
            float2 r7 = *(const float2*)&h1[(size_t)s7 * HID + t * 4];
            acc_h1frag(r0, acc); acc_h1frag(r1, acc);
            acc_h1frag(r2, acc); acc_h1frag(r3, acc);
            acc_h1frag(r4, acc); acc_h1frag(r5, acc);
            acc_h1frag(r6, acc); acc_h1frag(r7, acc);
        }
        for (; e < end; e++) {
            int s = __builtin_nontemporal_load(&sorted_src[e]);
            float2 r = *(const float2*)&h1[(size_t)s * HID + t * 4];
            acc_h1frag(r, acc);
        }
        __half2 o01 = __builtin_bit_cast(__half2, ro.x);
        __half2 o23 = __builtin_bit_cast(__half2, ro.y);
        float4 own = make_float4(__low2float(o01), __high2float(o01),
                                 __low2float(o23), __high2float(o23));
        *(float4*)&sA[nodeL][t * 4] = acc;
        *(float4*)&sB[nodeL][t * 4] = own;
    }
    __syncthreads();

    float h2r[4];
    if (live) {
        h2r[0] = sbl2[t * 4 + 0]; h2r[1] = sbl2[t * 4 + 1];
        h2r[2] = sbl2[t * 4 + 2]; h2r[3] = sbl2[t * 4 + 3];
#pragma unroll 8
        for (int k = 0; k < HID; k++) {
            float a = sA[nodeL][k];
            float b = sB[nodeL][k];
            float4 wl = *(const float4*)&sWl2[k * HID + t * 4];
            float4 wr = *(const float4*)&sWr2[k * HID + t * 4];
            h2r[0] += a * wl.x + b * wr.x;
            h2r[1] += a * wl.y + b * wr.y;
            h2r[2] += a * wl.z + b * wr.z;
            h2r[3] += a * wl.w + b * wr.w;
        }
#pragma unroll
        for (int jj = 0; jj < 4; jj++) h2r[jj] = h2r[jj] > 0.f ? h2r[jj] : LEAKY * h2r[jj];
    }
    __syncthreads();
    if (live) {
        float4 st = make_float4(h2r[0], h2r[1], h2r[2], h2r[3]);
        *(float4*)&sA[nodeL][t * 4] = st;
    }
    __syncthreads();

    if (live) {
        float4 acc = make_float4(0.f, 0.f, 0.f, 0.f);
#pragma unroll 8
        for (int k = 0; k < HID; k++) {
            float a = sA[nodeL][k];
            float4 w = *(const float4*)&sWse2[k * HID + t * 4];
            acc.x += a * w.x; acc.y += a * w.y;
            acc.z += a * w.z; acc.w += a * w.w;
        }
        float4 own = *(const float4*)&sB[nodeL][t * 4];
        own.x = salpha * own.x + acc.x * SE3NORM;
        own.y = salpha * own.y + acc.y * SE3NORM;
        own.z = salpha * own.z + acc.z * SE3NORM;
        own.w = salpha * own.w + acc.w * SE3NORM;
        *(float4*)&sB[nodeL][t * 4] = own;
    }
    __syncthreads();

    float acc4[4];
    acc4[0] = sb3[t * 4 + 0]; acc4[1] = sb3[t * 4 + 1];
    acc4[2] = sb3[t * 4 + 2]; acc4[3] = sb3[t * 4 + 3];
    if (live) {
#pragma unroll 8
        for (int k = 0; k < HID; k++) {
            float s = sB[nodeL][k];
            float4 w = *(const float4*)&sW3[k * HID + t * 4];
            acc4[0] += s * w.x; acc4[1] += s * w.y;
            acc4[2] += s * w.z; acc4[3] += s * w.w;
        }
    }
    float part = 0.f;
#pragma unroll
    for (int jj = 0; jj < 4; jj++)
        part += (acc4[jj] > 0.f ? acc4[jj] : 0.f) * sW4[t * 4 + jj];
    part += __shfl_xor(part, 1);
    part += __shfl_xor(part, 2);
    part += __shfl_xor(part, 4);
    if (live && t == 0) out[node] = part + sb4;
}

extern "C" void kernel_launch(void* const* d_in, const int* in_sizes, int n_in,
                              void* d_out, int out_size, void* d_ws, size_t ws_size,
                              hipStream_t stream) {
    const float* pos  = (const float*)d_in[0];
    const int*   ei   = (const int*)d_in[1];
    const float* Wl1  = (const float*)d_in[2];
    const float* bl1  = (const float*)d_in[3];
    const float* Wr1  = (const float*)d_in[4];
    const float* Wl2  = (const float*)d_in[5];
    const float* bl2  = (const float*)d_in[6];
    const float* Wr2  = (const float*)d_in[7];
    const float* Wse1 = (const float*)d_in[8];
    const float* Wse2 = (const float*)d_in[9];
    const float* W3   = (const float*)d_in[10];
    const float* b3   = (const float*)d_in[11];
    const float* W4   = (const float*)d_in[12];
    const float* b4   = (const float*)d_in[13];
    const float* alp  = (const float*)d_in[14];
    float* out = (float*)d_out;

    const int N = in_sizes[0] / 3;
    const int E = in_sizes[1] / 2;
    const int blk = 256;
    const size_t h1bytes = (size_t)N * HID * sizeof(__half);

    // ---- two-level bucket sort, no global atomics ----
    const int B1 = (N + NBK - 1) / NBK;
    const int M2 = B1 * GA;
    const int S2 = (M2 + SCAN_TILE - 1) / SCAN_TILE;
    {
        int* bh         = (int*)d_ws;
        int* bsum       = bh + M2;
        int* bucketed   = bsum + 256;
        int* sorted_src = bucketed + E;
        int* offsets    = sorted_src + E;
        uintptr_t hp = ((uintptr_t)(offsets + N + 1) + 15) & ~(uintptr_t)15;
        size_t need = (hp - (uintptr_t)d_ws) + h1bytes;
        const int chunk = (E + GA - 1) / GA;
        if (need <= ws_size && S2 <= 256 && B1 <= 1024 && chunk <= CHCAP) {
            __half* h1 = (__half*)hp;
            const size_t ldsB = (size_t)B1 * sizeof(int);
            // LDS for bscatter2: cur/hist/base (3*B1 ints) + perm (CHCAP u16)
            const size_t ldsB2 = (size_t)(3 * B1) * sizeof(int) + (size_t)CHCAP * sizeof(unsigned short);
            k_bhist<<<GA, 256, ldsB, stream>>>(ei, bh, E, B1, chunk);
            k_scan1<<<S2, 256, 0, stream>>>(bh, bsum, M2);
            k_scan2<<<1, 256, 0, stream>>>(bsum, S2);
            // (k_scan3 deleted: +bsum folded into k_bscatter2 / k_bsort)
            k_bscatter2<<<GA, 256, ldsB2, stream>>>(ei, bh, bsum, bucketed, E, B1, chunk);
            k_bsort<<<B1, 256, 0, stream>>>(bh, bsum, bucketed, sorted_src, offsets, E, N, B1);
            k_node1<<<(N + 31) / 32, 256, 0, stream>>>(offsets, sorted_src, pos,
                                                       Wl1, bl1, Wr1, Wse1, h1, N);
            k_node2out<<<(N + NPB2 - 1) / NPB2, 512, 0, stream>>>(offsets, sorted_src, h1,
                                                          Wl2, bl2, Wr2, Wse2,
                                                          W3, b3, W4, b4, alp, out, N);
            return;
        }
    }

    // ---- fallback: R4 global-atomic CSR build ----
    const int M = N + 1;
    const int B = (M + SCAN_TILE - 1) / SCAN_TILE;
    int* hist       = (int*)d_ws;
    int* offsets    = hist + M;   // unused (in-place scan) but keeps layout roomy
    int* bsum       = offsets + M;
    int* sorted_src = bsum + 256;
    int* aux        = sorted_src + E;
    uintptr_t hpA = ((uintptr_t)(aux + E) + 15) & ~(uintptr_t)15;
    uintptr_t hpB = ((uintptr_t)(aux + N) + 15) & ~(uintptr_t)15;
    size_t needA = (hpA - (uintptr_t)d_ws) + h1bytes;
    const bool useRank = (needA <= ws_size);
    __half* h1 = (__half*)(useRank ? hpA : hpB);

    hipMemsetAsync(hist, 0, (size_t)M * sizeof(int), stream);
    const int egrid4 = (E / 4 + blk) / blk;
    if (useRank) {
        k_hist_rank<<<egrid4, blk, 0, stream>>>(ei, hist, aux, E);
    } else {
        k_hist<<<egrid4, blk, 0, stream>>>(ei, hist, E);
    }
    k_scan1<<<B, 256, 0, stream>>>(hist, bsum, M);
    k_scan2<<<1, 256, 0, stream>>>(bsum, B);
    k_scan3<<<(M + blk - 1) / blk, blk, 0, stream>>>(hist, bsum, useRank ? nullptr : aux, M, N);
    int* offs = hist;
    if (useRank) {
        k_scatter_rank<<<egrid4, blk, 0, stream>>>(ei, offs, aux, sorted_src, E);
    } else {
        k_scatter_atomic<<<egrid4, blk, 0, stream>>>(ei, aux, sorted_src, E);
    }
    k_node1<<<(N + 31) / 32, 256, 0, stream>>>(offs, sorted_src, pos, Wl1, bl1, Wr1, Wse1, h1, N);
    k_node2out<<<(N + NPB2 - 1) / NPB2, 512, 0, stream>>>(offs, sorted_src, h1, Wl2, bl2, Wr2, Wse2,
                                                  W3, b3, W4, b4, alp, out, N);
}

// Round 12
// 241.323 us; speedup vs baseline: 1.0268x; 1.0268x over previous
//
// v12: build-side GRID-starvation fix. Rounds 10-11 attacked write-ordering and
// LDS-per-block occupancy — both flat, because k_bhist/k_bscatter2 ran only
// GA=320 blocks on 256 CUs (1.25 blocks/CU, ~1.25 waves/SIMD) and k_bsort 782
// blocks @256thr (3 waves/SIMD): grid-limited TLP, not cap-limited.
// Changes: GA 320->1024 (4 blocks/CU), k_scan2 handles 1024 tiles (4/thread),
// k_bsort 512 threads. k_node1 / k_node2out byte-identical anchors.
#include <hip/hip_runtime.h>
#include <hip/hip_fp16.h>

#define HID 32
#define LEAKY 0.01f
#define SE3NORM 0.17677669529663687f   // 1/sqrt(32)
#define SCAN_TILE 1024                 // elements per scan block (256 thr x 4)
#define NBK 128                        // nodes per fine bucket
#define GA 1024                        // pass-A blocks (chunk 2442 <= CHCAP)
#define CHCAP 8192                     // max staged elements (uint16 perm)
#define NPB2 64                        // nodes per block in k_node2out (512 threads)

// ======================= two-level bucket CSR build (no global atomics) =======================

// pass A1: per-block LDS histogram of coarse bucket (dst>>7); bh[b*GA + g] = count
__global__ void k_bhist(const int* __restrict__ ei, int* __restrict__ bh,
                        int E, int B1, int chunk) {
    extern __shared__ int lh[];                 // B1 ints
    int g = blockIdx.x;
    for (int i = threadIdx.x; i < B1; i += 256) lh[i] = 0;
    __syncthreads();
    int beg = g * chunk, end = min(E, beg + chunk);
    for (int e = beg + (int)threadIdx.x; e < end; e += 256)
        atomicAdd(&lh[ei[E + e] >> 7], 1);
    __syncthreads();
    for (int b = threadIdx.x; b < B1; b += 256) bh[b * GA + g] = lh[b];
}

// scan pass 1: per-tile exclusive scan IN PLACE + tile sums
__global__ void k_scan1(int* __restrict__ data, int* __restrict__ bsum, int M) {
    __shared__ int lds[256];
    int t = threadIdx.x;
    int base = blockIdx.x * SCAN_TILE + t * 4;
    int v0 = (base + 0 < M) ? data[base + 0] : 0;
    int v1 = (base + 1 < M) ? data[base + 1] : 0;
    int v2 = (base + 2 < M) ? data[base + 2] : 0;
    int v3 = (base + 3 < M) ? data[base + 3] : 0;
    int s = v0 + v1 + v2 + v3;
    lds[t] = s;
    __syncthreads();
    for (int off = 1; off < 256; off <<= 1) {
        int x = (t >= off) ? lds[t - off] : 0;
        __syncthreads();
        lds[t] += x;
        __syncthreads();
    }
    int ex = lds[t] - s;
    if (base + 0 < M) data[base + 0] = ex;
    if (base + 1 < M) data[base + 1] = ex + v0;
    if (base + 2 < M) data[base + 2] = ex + v0 + v1;
    if (base + 3 < M) data[base + 3] = ex + v0 + v1 + v2;
    if (t == 255) bsum[blockIdx.x] = lds[255];
}

// scan pass 2 v2: exclusive scan of tile sums (single block, B<=1024, 4/thread)
__global__ void k_scan2(int* __restrict__ bsum, int B) {
    __shared__ int lds[256];
    int t = threadIdx.x;
    int k0 = t * 4;
    int v0 = (k0 + 0 < B) ? bsum[k0 + 0] : 0;
    int v1 = (k0 + 1 < B) ? bsum[k0 + 1] : 0;
    int v2 = (k0 + 2 < B) ? bsum[k0 + 2] : 0;
    int v3 = (k0 + 3 < B) ? bsum[k0 + 3] : 0;
    int s = v0 + v1 + v2 + v3;
    lds[t] = s;
    __syncthreads();
    for (int off = 1; off < 256; off <<= 1) {
        int x = (t >= off) ? lds[t - off] : 0;
        __syncthreads();
        lds[t] += x;
        __syncthreads();
    }
    int ex = lds[t] - s;
    if (k0 + 0 < B) { bsum[k0 + 0] = ex; ex += v0; }
    if (k0 + 1 < B) { bsum[k0 + 1] = ex; ex += v1; }
    if (k0 + 2 < B) { bsum[k0 + 2] = ex; ex += v2; }
    if (k0 + 3 < B) { bsum[k0 + 3] = ex; ex += v3; }
}

// scan pass 3: add tile prefix in place (FALLBACK PATH ONLY)
__global__ void k_scan3(int* __restrict__ data, const int* __restrict__ bsum,
                        int* __restrict__ cursor, int M, int N) {
    int i = blockIdx.x * blockDim.x + threadIdx.x;
    if (i >= M) return;
    int off = data[i] + bsum[i / SCAN_TILE];
    data[i] = off;
    if (cursor && i < N) cursor[i] = off;
}

// pass A3: perm-staged ORDERED scatter (25 KB LDS); bh holds per-tile partial
// scans; +bsum[idx>>10] applied here. LDS: cur[B1]|hist[B1]|base[B1]|perm[CHCAP u16]
__global__ __launch_bounds__(256, 1) void k_bscatter2(
        const int* __restrict__ ei, const int* __restrict__ bh,
        const int* __restrict__ bsum,
        int* __restrict__ bucketed, int E, int B1, int chunk) {
    extern __shared__ int lh[];
    int* cur  = lh;
    int* hist = lh + B1;
    int* base = lh + 2 * B1;
    unsigned short* perm = (unsigned short*)(lh + 3 * B1);
    __shared__ int scanbuf[256];
    const int g = blockIdx.x;
    const int t = threadIdx.x;
    const int beg = g * chunk;
    const int end = min(E, beg + chunk);
    const int sz = end - beg;

    for (int b = t; b < B1; b += 256) {
        int idx = b * GA + g;
        cur[b] = bh[idx] + bsum[idx >> 10];      // SCAN_TILE == 1024
        hist[b] = 0;
    }
    __syncthreads();
    // pass A: coalesced dst read -> count
    for (int i = t; i < sz; i += 256)
        atomicAdd(&hist[ei[E + beg + i] >> 7], 1);
    __syncthreads();
    // exclusive scan of hist (B1 <= 1024): 4 buckets/thread serial + 256-scan
    {
        int k0 = t * 4;
        int c0 = (k0 + 0 < B1) ? hist[k0 + 0] : 0;
        int c1 = (k0 + 1 < B1) ? hist[k0 + 1] : 0;
        int c2 = (k0 + 2 < B1) ? hist[k0 + 2] : 0;
        int c3 = (k0 + 3 < B1) ? hist[k0 + 3] : 0;
        int ssum = c0 + c1 + c2 + c3;
        scanbuf[t] = ssum;
        __syncthreads();
        for (int off = 1; off < 256; off <<= 1) {
            int x = (t >= off) ? scanbuf[t - off] : 0;
            __syncthreads();
            scanbuf[t] += x;
            __syncthreads();
        }
        int ex = scanbuf[t] - ssum;
        if (k0 + 0 < B1) { base[k0 + 0] = ex; ex += c0; }
        if (k0 + 1 < B1) { base[k0 + 1] = ex; ex += c1; }
        if (k0 + 2 < B1) { base[k0 + 2] = ex; ex += c2; }
        if (k0 + 3 < B1) { base[k0 + 3] = ex; ex += c3; }
    }
    __syncthreads();
    for (int b = t; b < B1; b += 256) hist[b] = base[b];  // cursor
    __syncthreads();
    // pass B: coalesced dst re-read (L2-hot window) -> permutation
    for (int i = t; i < sz; i += 256) {
        int bid = ei[E + beg + i] >> 7;
        int p = atomicAdd(&hist[bid], 1);
        perm[p] = (unsigned short)i;
    }
    __syncthreads();
    // output: linear over output positions -> ordered global writes
    for (int p = t; p < sz; p += 256) {
        int i = perm[p];
        int d = ei[E + beg + i];
        int s = ei[beg + i];
        int bid = d >> 7;
        bucketed[cur[bid] + (p - base[bid])] = s | ((d & (NBK - 1)) << 24);
    }
}

// pass B: counting sort, 512 threads (8 waves/block -> 24 waves/CU at 3 blk/CU),
// perm-only LDS, ordered writes. Oversized buckets: unordered fallback.
__global__ __launch_bounds__(512, 1) void k_bsort(
        const int* __restrict__ bh, const int* __restrict__ bsum,
        const int* __restrict__ bucketed,
        int* __restrict__ sorted_src, int* __restrict__ offsets,
        int E, int N, int B1) {
    __shared__ int hist[NBK], sc[NBK], base[NBK];
    __shared__ unsigned short perm[CHCAP];         // 16 KB
    int b = blockIdx.x;
    int t = threadIdx.x;
    int i0 = b * GA;
    int bs = bh[i0] + bsum[i0 >> 10];
    int be;
    if (b == B1 - 1) be = E;
    else { int i1 = (b + 1) * GA; be = bh[i1] + bsum[i1 >> 10]; }
    int sz = be - bs;
    if (t < NBK) hist[t] = 0;
    __syncthreads();

    if (sz <= CHCAP) {
        for (int i = t; i < sz; i += 512)
            atomicAdd(&hist[bucketed[bs + i] >> 24], 1);
        __syncthreads();
        int v = (t < NBK) ? hist[t] : 0;
        if (t < NBK) sc[t] = v;
        __syncthreads();
        for (int off = 1; off < NBK; off <<= 1) {
            int x = (t < NBK && t >= off) ? sc[t - off] : 0;
            __syncthreads();
            if (t < NBK) sc[t] += x;
            __syncthreads();
        }
        if (t < NBK) base[t] = sc[t] - v;           // exclusive
        __syncthreads();
        if (t < NBK) hist[t] = base[t];             // cursor
        __syncthreads();
        for (int i = t; i < sz; i += 512) {
            int p = atomicAdd(&hist[bucketed[bs + i] >> 24], 1);
            perm[p] = (unsigned short)i;
        }
        __syncthreads();
        for (int p = t; p < sz; p += 512)           // ordered write
            sorted_src[bs + p] = bucketed[bs + perm[p]] & 0x00FFFFFF;
    } else {
        for (int e = bs + t; e < be; e += 512)
            atomicAdd(&hist[bucketed[e] >> 24], 1);
        __syncthreads();
        int v = (t < NBK) ? hist[t] : 0;
        if (t < NBK) sc[t] = v;
        __syncthreads();
        for (int off = 1; off < NBK; off <<= 1) {
            int x = (t < NBK && t >= off) ? sc[t - off] : 0;
            __syncthreads();
            if (t < NBK) sc[t] += x;
            __syncthreads();
        }
        if (t < NBK) base[t] = sc[t] - v;
        __syncthreads();
        if (t < NBK) hist[t] = base[t];
        __syncthreads();
        for (int e = bs + t; e < be; e += 512) {
            int pv = bucketed[e];
            int p = atomicAdd(&hist[pv >> 24], 1);
            sorted_src[bs + p] = pv & 0x00FFFFFF;
        }
    }
    int node = b * NBK + t;
    if (t < NBK && node < N) offsets[node] = bs + base[t];
    if (b == B1 - 1 && t == 0) offsets[N] = E;
}

// ======================= fallback CSR build (global atomics, R4 path) =======================
__global__ void k_hist_rank(const int* __restrict__ ei, int* __restrict__ hist,
                            int* __restrict__ rank, int E) {
    int base = (blockIdx.x * blockDim.x + threadIdx.x) * 4;
#pragma unroll
    for (int u = 0; u < 4; u++) {
        int e = base + u;
        if (e < E) rank[e] = atomicAdd(&hist[ei[E + e]], 1);
    }
}
__global__ void k_hist(const int* __restrict__ ei, int* __restrict__ hist, int E) {
    int base = (blockIdx.x * blockDim.x + threadIdx.x) * 4;
#pragma unroll
    for (int u = 0; u < 4; u++) {
        int e = base + u;
        if (e < E) atomicAdd(&hist[ei[E + e]], 1);
    }
}
__global__ void k_scatter_rank(const int* __restrict__ ei, const int* __restrict__ offsets,
                               const int* __restrict__ rank, int* __restrict__ sorted_src, int E) {
    int base = (blockIdx.x * blockDim.x + threadIdx.x) * 4;
#pragma unroll
    for (int u = 0; u < 4; u++) {
        int e = base + u;
        if (e < E) sorted_src[offsets[ei[E + e]] + rank[e]] = ei[e];
    }
}
__global__ void k_scatter_atomic(const int* __restrict__ ei, int* __restrict__ cursor,
                                 int* __restrict__ sorted_src, int E) {
    int base = (blockIdx.x * blockDim.x + threadIdx.x) * 4;
#pragma unroll
    for (int u = 0; u < 4; u++) {
        int e = base + u;
        if (e < E) {
            int p = atomicAdd(&cursor[ei[E + e]], 1);
            sorted_src[p] = ei[e];
        }
    }
}

// ======================= node-level fused kernels =======================
// layer 1 (round-9 verified): 8 thr/node, shfl-reduced partials, b128 weight reads.
__global__ __launch_bounds__(256, 1) void k_node1(
                        const int* __restrict__ offsets, const int* __restrict__ sorted_src,
                        const float* __restrict__ pos,
                        const float* __restrict__ Wl1, const float* __restrict__ bl1,
                        const float* __restrict__ Wr1, const float* __restrict__ Wse1,
                        __half* __restrict__ h1, int N) {
    __shared__ float sWl1[2 * HID], sWr1[2 * HID], sbl1[HID], sWse1[HID * HID];
    __shared__ float sH[32][HID + 4];
    for (int i = threadIdx.x; i < 2 * HID; i += blockDim.x) { sWl1[i] = Wl1[i]; sWr1[i] = Wr1[i]; }
    for (int i = threadIdx.x; i < HID; i += blockDim.x) sbl1[i] = bl1[i];
    for (int i = threadIdx.x; i < HID * HID; i += blockDim.x) sWse1[i] = Wse1[i];
    __syncthreads();

    const int lt = threadIdx.x;
    const int nodeL = lt >> 3;
    const int t = lt & 7;
    const int node = blockIdx.x * 32 + nodeL;
    const bool live = node < N;

    float a0 = 0.f, a1 = 0.f;
    if (live) {
        int beg = offsets[node], end = offsets[node + 1];
        for (int e = beg + t; e < end; e += 8) {
            int s = sorted_src[e];
            a0 += pos[s * 3];
            a1 += pos[s * 3 + 1];
        }
    }
    a0 += __shfl_xor(a0, 1); a1 += __shfl_xor(a1, 1);
    a0 += __shfl_xor(a0, 2); a1 += __shfl_xor(a1, 2);
    a0 += __shfl_xor(a0, 4); a1 += __shfl_xor(a1, 4);

    if (live) {
        float x0 = pos[3 * node], x1 = pos[3 * node + 1];
#pragma unroll
        for (int jj = 0; jj < 4; jj++) {
            int k = t * 4 + jj;
            float v = a0 * sWl1[k] + a1 * sWl1[HID + k] + sbl1[k] + x0 * sWr1[k] + x1 * sWr1[HID + k];
            sH[nodeL][k] = v > 0.f ? v : LEAKY * v;
        }
    }
    __syncthreads();

    if (live) {
        float4 acc = make_float4(0.f, 0.f, 0.f, 0.f);
#pragma unroll 8
        for (int k = 0; k < HID; k++) {
            float hk = sH[nodeL][k];
            float4 w = *(const float4*)&sWse1[k * HID + t * 4];
            acc.x += hk * w.x; acc.y += hk * w.y;
            acc.z += hk * w.z; acc.w += hk * w.w;
        }
        union Pack4 { __half h[4]; float2 v; } p;
        p.h[0] = __float2half(acc.x * SE3NORM);
        p.h[1] = __float2half(acc.y * SE3NORM);
        p.h[2] = __float2half(acc.z * SE3NORM);
        p.h[3] = __float2half(acc.w * SE3NORM);
        *(float2*)&h1[(size_t)node * HID + t * 4] = p.v;
    }
}

// accumulate an 8-byte h1 fragment (4 halves in a float2)
__device__ __forceinline__ void acc_h1frag(float2 r, float4& acc) {
    __half2 p01 = __builtin_bit_cast(__half2, r.x);
    __half2 p23 = __builtin_bit_cast(__half2, r.y);
    acc.x += __low2float(p01); acc.y += __high2float(p01);
    acc.z += __low2float(p23); acc.w += __high2float(p23);
}

// layer 2 + head (round-6/9 verified 74 us, bytes/BW-bound). Untouched.
__global__ __launch_bounds__(512, 1) void k_node2out(
                           const int* __restrict__ offsets, const int* __restrict__ sorted_src,
                           const __half* __restrict__ h1,
                           const float* __restrict__ Wl2, const float* __restrict__ bl2,
                           const float* __restrict__ Wr2, const float* __restrict__ Wse2,
                           const float* __restrict__ W3, const float* __restrict__ b3,
                           const float* __restrict__ W4, const float* __restrict__ b4,
                           const float* __restrict__ alpha_p,
                           float* __restrict__ out, int N) {
    __shared__ float sWl2[HID * HID], sWr2[HID * HID], sWse2[HID * HID], sW3[HID * HID];
    __shared__ float sbl2[HID], sb3[HID], sW4[HID];
    __shared__ float sb4, salpha;
    __shared__ float sA[NPB2][HID + 4], sB[NPB2][HID + 4];
    for (int i = threadIdx.x; i < HID * HID; i += blockDim.x) {
        sWl2[i] = Wl2[i]; sWr2[i] = Wr2[i]; sWse2[i] = Wse2[i]; sW3[i] = W3[i];
    }
    for (int i = threadIdx.x; i < HID; i += blockDim.x) { sbl2[i] = bl2[i]; sb3[i] = b3[i]; sW4[i] = W4[i]; }
    if (threadIdx.x == 0) { sb4 = b4[0]; salpha = alpha_p[0]; }
    __syncthreads();

    const int lt = threadIdx.x;
    const int nodeL = lt >> 3;       // 0..63
    const int t = lt & 7;
    const int node = blockIdx.x * NPB2 + nodeL;
    const bool live = node < N;

    if (live) {
        float2 ro = *(const float2*)&h1[(size_t)node * HID + t * 4];

        int beg = offsets[node], end = offsets[node + 1];
        float4 acc = make_float4(0.f, 0.f, 0.f, 0.f);
        int e = beg;
        for (; e + 8 <= end; e += 8) {
            int s0 = __builtin_nontemporal_load(&sorted_src[e + 0]);
            int s1 = __builtin_nontemporal_load(&sorted_src[e + 1]);
            int s2 = __builtin_nontemporal_load(&sorted_src[e + 2]);
            int s3 = __builtin_nontemporal_load(&sorted_src[e + 3]);
            int s4 = __builtin_nontemporal_load(&sorted_src[e + 4]);
            int s5 = __builtin_nontemporal_load(&sorted_src[e + 5]);
            int s6 = __builtin_nontemporal_load(&sorted_src[e + 6]);
            int s7 = __builtin_nontemporal_load(&sorted_src[e + 7]);
            float2 r0 = *(const float2*)&h1[(size_t)s0 * HID + t * 4];
            float2 r1 = *(const float2*)&h1[(size_t)s1 * HID + t * 4];
            float2 r2 = *(const float2*)&h1[(size_t)s2 * HID + t * 4];
            float2 r3 = *(const float2*)&h1[(size_t)s3 * HID + t * 4];
            float2 r4 = *(const float2*)&h1[(size_t)s4 * HID + t * 4];
            float2 r5 = *(const float2*)&h1[(size_t)s5 * HID + t * 4];
            float2 r6 = *(const float2*)&h1[(size_t)s6 * HID + t * 4];
            float2 r7 = *(const float2*)&h1[(size_t)s7 * HID + t * 4];
            acc_h1frag(r0, acc); acc_h1frag(r1, acc);
            acc_h1frag(r2, acc); acc_h1frag(r3, acc);
            acc_h1frag(r4, acc); acc_h1frag(r5, acc);
            acc_h1frag(r6, acc); acc_h1frag(r7, acc);
        }
        for (; e < end; e++) {
            int s = __builtin_nontemporal_load(&sorted_src[e]);
            float2 r = *(const float2*)&h1[(size_t)s * HID + t * 4];
            acc_h1frag(r, acc);
        }
        __half2 o01 = __builtin_bit_cast(__half2, ro.x);
        __half2 o23 = __builtin_bit_cast(__half2, ro.y);
        float4 own = make_float4(__low2float(o01), __high2float(o01),
                                 __low2float(o23), __high2float(o23));
        *(float4*)&sA[nodeL][t * 4] = acc;
        *(float4*)&sB[nodeL][t * 4] = own;
    }
    __syncthreads();

    float h2r[4];
    if (live) {
        h2r[0] = sbl2[t * 4 + 0]; h2r[1] = sbl2[t * 4 + 1];
        h2r[2] = sbl2[t * 4 + 2]; h2r[3] = sbl2[t * 4 + 3];
#pragma unroll 8
        for (int k = 0; k < HID; k++) {
            float a = sA[nodeL][k];
            float b = sB[nodeL][k];
            float4 wl = *(const float4*)&sWl2[k * HID + t * 4];
            float4 wr = *(const float4*)&sWr2[k * HID + t * 4];
            h2r[0] += a * wl.x + b * wr.x;
            h2r[1] += a * wl.y + b * wr.y;
            h2r[2] += a * wl.z + b * wr.z;
            h2r[3] += a * wl.w + b * wr.w;
        }
#pragma unroll
        for (int jj = 0; jj < 4; jj++) h2r[jj] = h2r[jj] > 0.f ? h2r[jj] : LEAKY * h2r[jj];
    }
    __syncthreads();
    if (live) {
        float4 st = make_float4(h2r[0], h2r[1], h2r[2], h2r[3]);
        *(float4*)&sA[nodeL][t * 4] = st;
    }
    __syncthreads();

    if (live) {
        float4 acc = make_float4(0.f, 0.f, 0.f, 0.f);
#pragma unroll 8
        for (int k = 0; k < HID; k++) {
            float a = sA[nodeL][k];
            float4 w = *(const float4*)&sWse2[k * HID + t * 4];
            acc.x += a * w.x; acc.y += a * w.y;
            acc.z += a * w.z; acc.w += a * w.w;
        }
        float4 own = *(const float4*)&sB[nodeL][t * 4];
        own.x = salpha * own.x + acc.x * SE3NORM;
        own.y = salpha * own.y + acc.y * SE3NORM;
        own.z = salpha * own.z + acc.z * SE3NORM;
        own.w = salpha * own.w + acc.w * SE3NORM;
        *(float4*)&sB[nodeL][t * 4] = own;
    }
    __syncthreads();

    float acc4[4];
    acc4[0] = sb3[t * 4 + 0]; acc4[1] = sb3[t * 4 + 1];
    acc4[2] = sb3[t * 4 + 2]; acc4[3] = sb3[t * 4 + 3];
    if (live) {
#pragma unroll 8
        for (int k = 0; k < HID; k++) {
            float s = sB[nodeL][k];
            float4 w = *(const float4*)&sW3[k * HID + t * 4];
            acc4[0] += s * w.x; acc4[1] += s * w.y;
            acc4[2] += s * w.z; acc4[3] += s * w.w;
        }
    }
    float part = 0.f;
#pragma unroll
    for (int jj = 0; jj < 4; jj++)
        part += (acc4[jj] > 0.f ? acc4[jj] : 0.f) * sW4[t * 4 + jj];
    part += __shfl_xor(part, 1);
    part += __shfl_xor(part, 2);
    part += __shfl_xor(part, 4);
    if (live && t == 0) out[node] = part + sb4;
}

extern "C" void kernel_launch(void* const* d_in, const int* in_sizes, int n_in,
                              void* d_out, int out_size, void* d_ws, size_t ws_size,
                              hipStream_t stream) {
    const float* pos  = (const float*)d_in[0];
    const int*   ei   = (const int*)d_in[1];
    const float* Wl1  = (const float*)d_in[2];
    const float* bl1  = (const float*)d_in[3];
    const float* Wr1  = (const float*)d_in[4];
    const float* Wl2  = (const float*)d_in[5];
    const float* bl2  = (const float*)d_in[6];
    const float* Wr2  = (const float*)d_in[7];
    const float* Wse1 = (const float*)d_in[8];
    const float* Wse2 = (const float*)d_in[9];
    const float* W3   = (const float*)d_in[10];
    const float* b3   = (const float*)d_in[11];
    const float* W4   = (const float*)d_in[12];
    const float* b4   = (const float*)d_in[13];
    const float* alp  = (const float*)d_in[14];
    float* out = (float*)d_out;

    const int N = in_sizes[0] / 3;
    const int E = in_sizes[1] / 2;
    const int blk = 256;
    const size_t h1bytes = (size_t)N * HID * sizeof(__half);

    // ---- two-level bucket sort, no global atomics ----
    const int B1 = (N + NBK - 1) / NBK;
    const int M2 = B1 * GA;
    const int S2 = (M2 + SCAN_TILE - 1) / SCAN_TILE;
    {
        int* bh         = (int*)d_ws;
        int* bsum       = bh + M2;
        int* bucketed   = bsum + 1024;
        int* sorted_src = bucketed + E;
        int* offsets    = sorted_src + E;
        uintptr_t hp = ((uintptr_t)(offsets + N + 1) + 15) & ~(uintptr_t)15;
        size_t need = (hp - (uintptr_t)d_ws) + h1bytes;
        const int chunk = (E + GA - 1) / GA;
        if (need <= ws_size && S2 <= 1024 && B1 <= 1024 && chunk <= CHCAP) {
            __half* h1 = (__half*)hp;
            const size_t ldsB = (size_t)B1 * sizeof(int);
            // LDS for bscatter2: cur/hist/base (3*B1 ints) + perm (CHCAP u16)
            const size_t ldsB2 = (size_t)(3 * B1) * sizeof(int) + (size_t)CHCAP * sizeof(unsigned short);
            k_bhist<<<GA, 256, ldsB, stream>>>(ei, bh, E, B1, chunk);
            k_scan1<<<S2, 256, 0, stream>>>(bh, bsum, M2);
            k_scan2<<<1, 256, 0, stream>>>(bsum, S2);
            k_bscatter2<<<GA, 256, ldsB2, stream>>>(ei, bh, bsum, bucketed, E, B1, chunk);
            k_bsort<<<B1, 512, 0, stream>>>(bh, bsum, bucketed, sorted_src, offsets, E, N, B1);
            k_node1<<<(N + 31) / 32, 256, 0, stream>>>(offsets, sorted_src, pos,
                                                       Wl1, bl1, Wr1, Wse1, h1, N);
            k_node2out<<<(N + NPB2 - 1) / NPB2, 512, 0, stream>>>(offsets, sorted_src, h1,
                                                          Wl2, bl2, Wr2, Wse2,
                                                          W3, b3, W4, b4, alp, out, N);
            return;
        }
    }

    // ---- fallback: R4 global-atomic CSR build ----
    const int M = N + 1;
    const int B = (M + SCAN_TILE - 1) / SCAN_TILE;
    int* hist       = (int*)d_ws;
    int* offsets    = hist + M;   // unused (in-place scan) but keeps layout roomy
    int* bsum       = offsets + M;
    int* sorted_src = bsum + 1024;
    int* aux        = sorted_src + E;
    uintptr_t hpA = ((uintptr_t)(aux + E) + 15) & ~(uintptr_t)15;
    uintptr_t hpB = ((uintptr_t)(aux + N) + 15) & ~(uintptr_t)15;
    size_t needA = (hpA - (uintptr_t)d_ws) + h1bytes;
    const bool useRank = (needA <= ws_size);
    __half* h1 = (__half*)(useRank ? hpA : hpB);

    hipMemsetAsync(hist, 0, (size_t)M * sizeof(int), stream);
    const int egrid4 = (E / 4 + blk) / blk;
    if (useRank) {
        k_hist_rank<<<egrid4, blk, 0, stream>>>(ei, hist, aux, E);
    } else {
        k_hist<<<egrid4, blk, 0, stream>>>(ei, hist, E);
    }
    k_scan1<<<B, 256, 0, stream>>>(hist, bsum, M);
    k_scan2<<<1, 256, 0, stream>>>(bsum, B);
    k_scan3<<<(M + blk - 1) / blk, blk, 0, stream>>>(hist, bsum, useRank ? nullptr : aux, M, N);
    int* offs = hist;
    if (useRank) {
        k_scatter_rank<<<egrid4, blk, 0, stream>>>(ei, offs, aux, sorted_src, E);
    } else {
        k_scatter_atomic<<<egrid4, blk, 0, stream>>>(ei, aux, sorted_src, E);
    }
    k_node1<<<(N + 31) / 32, 256, 0, stream>>>(offs, sorted_src, pos, Wl1, bl1, Wr1, Wse1, h1, N);
    k_node2out<<<(N + NPB2 - 1) / NPB2, 512, 0, stream>>>(offs, sorted_src, h1, Wl2, bl2, Wr2, Wse2,
                                                  W3, b3, W4, b4, alp, out, N);
}

// Round 13
// 237.611 us; speedup vs baseline: 1.0428x; 1.0156x over previous
//
// v13: POST-SORT fusion of layer-1 into k_bsort (deletes k_node1: one launch +
// a 10 MB sorted_src re-read). Unlike round-6's failed PRE-sort fusion (LDS
// float atomics + cold pos gathers inside the histogram loop, +35 us), the
// tail fusion uses the block's own segment table: 4 thr/node strided gather
// over the L2-resident 1.2 MB pos table + shfl reduce, then the standard h1
// compute. k_node2out byte-identical anchor (line-fill-concurrency-bound).
// Build rounds 10-12 (ordering/LDS/grid) were all flat: the 167-us build is
// structural -> attack pass count.
#include <hip/hip_runtime.h>
#include <hip/hip_fp16.h>

#define HID 32
#define LEAKY 0.01f
#define SE3NORM 0.17677669529663687f   // 1/sqrt(32)
#define SCAN_TILE 1024                 // elements per scan block (256 thr x 4)
#define NBK 128                        // nodes per fine bucket
#define GA 1024                        // pass-A blocks (chunk 2442 <= CHCAP)
#define CHCAP 8192                     // max staged elements (uint16 perm)
#define NPB2 64                        // nodes per block in k_node2out (512 threads)

// ======================= two-level bucket CSR build (no global atomics) =======================

// pass A1: per-block LDS histogram of coarse bucket (dst>>7); bh[b*GA + g] = count
__global__ void k_bhist(const int* __restrict__ ei, int* __restrict__ bh,
                        int E, int B1, int chunk) {
    extern __shared__ int lh[];                 // B1 ints
    int g = blockIdx.x;
    for (int i = threadIdx.x; i < B1; i += 256) lh[i] = 0;
    __syncthreads();
    int beg = g * chunk, end = min(E, beg + chunk);
    for (int e = beg + (int)threadIdx.x; e < end; e += 256)
        atomicAdd(&lh[ei[E + e] >> 7], 1);
    __syncthreads();
    for (int b = threadIdx.x; b < B1; b += 256) bh[b * GA + g] = lh[b];
}

// scan pass 1: per-tile exclusive scan IN PLACE + tile sums
__global__ void k_scan1(int* __restrict__ data, int* __restrict__ bsum, int M) {
    __shared__ int lds[256];
    int t = threadIdx.x;
    int base = blockIdx.x * SCAN_TILE + t * 4;
    int v0 = (base + 0 < M) ? data[base + 0] : 0;
    int v1 = (base + 1 < M) ? data[base + 1] : 0;
    int v2 = (base + 2 < M) ? data[base + 2] : 0;
    int v3 = (base + 3 < M) ? data[base + 3] : 0;
    int s = v0 + v1 + v2 + v3;
    lds[t] = s;
    __syncthreads();
    for (int off = 1; off < 256; off <<= 1) {
        int x = (t >= off) ? lds[t - off] : 0;
        __syncthreads();
        lds[t] += x;
        __syncthreads();
    }
    int ex = lds[t] - s;
    if (base + 0 < M) data[base + 0] = ex;
    if (base + 1 < M) data[base + 1] = ex + v0;
    if (base + 2 < M) data[base + 2] = ex + v0 + v1;
    if (base + 3 < M) data[base + 3] = ex + v0 + v1 + v2;
    if (t == 255) bsum[blockIdx.x] = lds[255];
}

// scan pass 2: exclusive scan of tile sums (single block, B<=1024, 4/thread)
__global__ void k_scan2(int* __restrict__ bsum, int B) {
    __shared__ int lds[256];
    int t = threadIdx.x;
    int k0 = t * 4;
    int v0 = (k0 + 0 < B) ? bsum[k0 + 0] : 0;
    int v1 = (k0 + 1 < B) ? bsum[k0 + 1] : 0;
    int v2 = (k0 + 2 < B) ? bsum[k0 + 2] : 0;
    int v3 = (k0 + 3 < B) ? bsum[k0 + 3] : 0;
    int s = v0 + v1 + v2 + v3;
    lds[t] = s;
    __syncthreads();
    for (int off = 1; off < 256; off <<= 1) {
        int x = (t >= off) ? lds[t - off] : 0;
        __syncthreads();
        lds[t] += x;
        __syncthreads();
    }
    int ex = lds[t] - s;
    if (k0 + 0 < B) { bsum[k0 + 0] = ex; ex += v0; }
    if (k0 + 1 < B) { bsum[k0 + 1] = ex; ex += v1; }
    if (k0 + 2 < B) { bsum[k0 + 2] = ex; ex += v2; }
    if (k0 + 3 < B) { bsum[k0 + 3] = ex; ex += v3; }
}

// scan pass 3: add tile prefix in place (FALLBACK PATH ONLY)
__global__ void k_scan3(int* __restrict__ data, const int* __restrict__ bsum,
                        int* __restrict__ cursor, int M, int N) {
    int i = blockIdx.x * blockDim.x + threadIdx.x;
    if (i >= M) return;
    int off = data[i] + bsum[i / SCAN_TILE];
    data[i] = off;
    if (cursor && i < N) cursor[i] = off;
}

// pass A3: perm-staged ORDERED scatter; bh holds per-tile partial scans;
// +bsum[idx>>10] applied here. LDS: cur[B1]|hist[B1]|base[B1]|perm[CHCAP u16]
__global__ __launch_bounds__(256, 1) void k_bscatter2(
        const int* __restrict__ ei, const int* __restrict__ bh,
        const int* __restrict__ bsum,
        int* __restrict__ bucketed, int E, int B1, int chunk) {
    extern __shared__ int lh[];
    int* cur  = lh;
    int* hist = lh + B1;
    int* base = lh + 2 * B1;
    unsigned short* perm = (unsigned short*)(lh + 3 * B1);
    __shared__ int scanbuf[256];
    const int g = blockIdx.x;
    const int t = threadIdx.x;
    const int beg = g * chunk;
    const int end = min(E, beg + chunk);
    const int sz = end - beg;

    for (int b = t; b < B1; b += 256) {
        int idx = b * GA + g;
        cur[b] = bh[idx] + bsum[idx >> 10];      // SCAN_TILE == 1024
        hist[b] = 0;
    }
    __syncthreads();
    for (int i = t; i < sz; i += 256)
        atomicAdd(&hist[ei[E + beg + i] >> 7], 1);
    __syncthreads();
    {
        int k0 = t * 4;
        int c0 = (k0 + 0 < B1) ? hist[k0 + 0] : 0;
        int c1 = (k0 + 1 < B1) ? hist[k0 + 1] : 0;
        int c2 = (k0 + 2 < B1) ? hist[k0 + 2] : 0;
        int c3 = (k0 + 3 < B1) ? hist[k0 + 3] : 0;
        int ssum = c0 + c1 + c2 + c3;
        scanbuf[t] = ssum;
        __syncthreads();
        for (int off = 1; off < 256; off <<= 1) {
            int x = (t >= off) ? scanbuf[t - off] : 0;
            __syncthreads();
            scanbuf[t] += x;
            __syncthreads();
        }
        int ex = scanbuf[t] - ssum;
        if (k0 + 0 < B1) { base[k0 + 0] = ex; ex += c0; }
        if (k0 + 1 < B1) { base[k0 + 1] = ex; ex += c1; }
        if (k0 + 2 < B1) { base[k0 + 2] = ex; ex += c2; }
        if (k0 + 3 < B1) { base[k0 + 3] = ex; ex += c3; }
    }
    __syncthreads();
    for (int b = t; b < B1; b += 256) hist[b] = base[b];  // cursor
    __syncthreads();
    for (int i = t; i < sz; i += 256) {
        int bid = ei[E + beg + i] >> 7;
        int p = atomicAdd(&hist[bid], 1);
        perm[p] = (unsigned short)i;
    }
    __syncthreads();
    for (int p = t; p < sz; p += 256) {
        int i = perm[p];
        int d = ei[E + beg + i];
        int s = ei[beg + i];
        int bid = d >> 7;
        bucketed[cur[bid] + (p - base[bid])] = s | ((d & (NBK - 1)) << 24);
    }
}

// pass B + FUSED LAYER 1: counting sort (512 thr, perm, ordered writes) then,
// with segment table still in LDS: agg1 (4 thr/node over the hot sorted
// window, shfl-reduced) and h1 = leaky(agg1@Wl1+bl1+x@Wr1)@Wse1*SE3NORM.
// Static LDS ~33 KB -> grid-limited 3 blocks/CU (24 waves) unchanged.
__global__ __launch_bounds__(512, 1) void k_bsortn1(
        const int* __restrict__ bh, const int* __restrict__ bsum,
        const int* __restrict__ bucketed,
        const float* __restrict__ pos,
        const float* __restrict__ Wl1, const float* __restrict__ bl1,
        const float* __restrict__ Wr1, const float* __restrict__ Wse1,
        int* __restrict__ sorted_src, int* __restrict__ offsets,
        __half* __restrict__ h1, int E, int N, int B1) {
    __shared__ int hist[NBK], sc[NBK], base[NBK];
    __shared__ unsigned short perm[CHCAP];         // 16 KB
    __shared__ float aggx[NBK], aggy[NBK];
    __shared__ float sWl1[2 * HID], sWr1[2 * HID], sbl1[HID], sWse1[HID * HID];
    __shared__ float sH[64][HID + 4];              // 9.2 KB (2 chunks of 64 nodes)
    int b = blockIdx.x;
    int t = threadIdx.x;
    // weight preload (visible after any later barrier)
    for (int i = t; i < 2 * HID; i += 512) { sWl1[i] = Wl1[i]; sWr1[i] = Wr1[i]; }
    for (int i = t; i < HID; i += 512) sbl1[i] = bl1[i];
    for (int i = t; i < HID * HID; i += 512) sWse1[i] = Wse1[i];

    int i0 = b * GA;
    int bs = bh[i0] + bsum[i0 >> 10];
    int be;
    if (b == B1 - 1) be = E;
    else { int i1 = (b + 1) * GA; be = bh[i1] + bsum[i1 >> 10]; }
    int sz = be - bs;
    if (t < NBK) hist[t] = 0;
    __syncthreads();

    if (sz <= CHCAP) {
        for (int i = t; i < sz; i += 512)
            atomicAdd(&hist[bucketed[bs + i] >> 24], 1);
        __syncthreads();
        int v = (t < NBK) ? hist[t] : 0;
        if (t < NBK) sc[t] = v;
        __syncthreads();
        for (int off = 1; off < NBK; off <<= 1) {
            int x = (t < NBK && t >= off) ? sc[t - off] : 0;
            __syncthreads();
            if (t < NBK) sc[t] += x;
            __syncthreads();
        }
        if (t < NBK) base[t] = sc[t] - v;           // exclusive
        __syncthreads();
        if (t < NBK) hist[t] = base[t];             // cursor -> ends as segment END
        __syncthreads();
        for (int i = t; i < sz; i += 512) {
            int p = atomicAdd(&hist[bucketed[bs + i] >> 24], 1);
            perm[p] = (unsigned short)i;
        }
        __syncthreads();
        for (int p = t; p < sz; p += 512)           // ordered write
            sorted_src[bs + p] = bucketed[bs + perm[p]] & 0x00FFFFFF;
    } else {
        for (int e = bs + t; e < be; e += 512)
            atomicAdd(&hist[bucketed[e] >> 24], 1);
        __syncthreads();
        int v = (t < NBK) ? hist[t] : 0;
        if (t < NBK) sc[t] = v;
        __syncthreads();
        for (int off = 1; off < NBK; off <<= 1) {
            int x = (t < NBK && t >= off) ? sc[t - off] : 0;
            __syncthreads();
            if (t < NBK) sc[t] += x;
            __syncthreads();
        }
        if (t < NBK) base[t] = sc[t] - v;
        __syncthreads();
        if (t < NBK) hist[t] = base[t];
        __syncthreads();
        for (int e = bs + t; e < be; e += 512) {
            int pv = bucketed[e];
            int p = atomicAdd(&hist[pv >> 24], 1);
            sorted_src[bs + p] = pv & 0x00FFFFFF;
        }
    }
    int nodeg = b * NBK + t;
    if (t < NBK && nodeg < N) offsets[nodeg] = bs + base[t];
    if (b == B1 - 1 && t == 0) offsets[N] = E;

    // ---- fused layer 1 ----
    // barrier: (a) sorted_src writes drained (vmcnt(0)+s_barrier; same-CU L1 is
    // coherent within the workgroup), (b) hist[] = segment ends stable.
    __syncthreads();

    // agg1: 4 threads per node, strided over the node's sorted segment
    {
        const int dl = t >> 2;                      // 0..127
        const int lane = t & 3;
        const int sbeg = bs + base[dl];
        const int cnt = hist[dl] - base[dl];        // hist ended as END cursor
        float a0 = 0.f, a1 = 0.f;
        for (int i = lane; i < cnt; i += 4) {
            int s = sorted_src[sbeg + i];           // L1/L2-hot (just written)
            a0 += pos[s * 3];
            a1 += pos[s * 3 + 1];
        }
        a0 += __shfl_xor(a0, 1); a1 += __shfl_xor(a1, 1);
        a0 += __shfl_xor(a0, 2); a1 += __shfl_xor(a1, 2);
        if (lane == 0) { aggx[dl] = a0; aggy[dl] = a1; }
    }
    __syncthreads();

    // h1 for the block's 128 nodes, 2 chunks of 64 (8 thr/node pattern)
    const int nodeL = t >> 3;        // 0..63
    const int tt = t & 7;
    for (int c = 0; c < 2; c++) {
        const int dl = c * 64 + nodeL;
        const int node = b * NBK + dl;
        const bool live = node < N;
        if (live) {
            float a0 = aggx[dl], a1 = aggy[dl];
            float x0 = pos[3 * node], x1 = pos[3 * node + 1];
#pragma unroll
            for (int jj = 0; jj < 4; jj++) {
                int k = tt * 4 + jj;
                float v = a0 * sWl1[k] + a1 * sWl1[HID + k] + sbl1[k]
                        + x0 * sWr1[k] + x1 * sWr1[HID + k];
                sH[nodeL][k] = v > 0.f ? v : LEAKY * v;
            }
        }
        __syncthreads();
        if (live) {
            float4 acc = make_float4(0.f, 0.f, 0.f, 0.f);
#pragma unroll 8
            for (int k = 0; k < HID; k++) {
                float hk = sH[nodeL][k];
                float4 w = *(const float4*)&sWse1[k * HID + tt * 4];
                acc.x += hk * w.x; acc.y += hk * w.y;
                acc.z += hk * w.z; acc.w += hk * w.w;
            }
            union Pack4 { __half h[4]; float2 v; } p;
            p.h[0] = __float2half(acc.x * SE3NORM);
            p.h[1] = __float2half(acc.y * SE3NORM);
            p.h[2] = __float2half(acc.z * SE3NORM);
            p.h[3] = __float2half(acc.w * SE3NORM);
            *(float2*)&h1[(size_t)node * HID + tt * 4] = p.v;
        }
        __syncthreads();             // sH reused by next chunk
    }
}

// ======================= fallback CSR build (global atomics, R4 path) =======================
__global__ void k_hist_rank(const int* __restrict__ ei, int* __restrict__ hist,
                            int* __restrict__ rank, int E) {
    int base = (blockIdx.x * blockDim.x + threadIdx.x) * 4;
#pragma unroll
    for (int u = 0; u < 4; u++) {
        int e = base + u;
        if (e < E) rank[e] = atomicAdd(&hist[ei[E + e]], 1);
    }
}
__global__ void k_hist(const int* __restrict__ ei, int* __restrict__ hist, int E) {
    int base = (blockIdx.x * blockDim.x + threadIdx.x) * 4;
#pragma unroll
    for (int u = 0; u < 4; u++) {
        int e = base + u;
        if (e < E) atomicAdd(&hist[ei[E + e]], 1);
    }
}
__global__ void k_scatter_rank(const int* __restrict__ ei, const int* __restrict__ offsets,
                               const int* __restrict__ rank, int* __restrict__ sorted_src, int E) {
    int base = (blockIdx.x * blockDim.x + threadIdx.x) * 4;
#pragma unroll
    for (int u = 0; u < 4; u++) {
        int e = base + u;
        if (e < E) sorted_src[offsets[ei[E + e]] + rank[e]] = ei[e];
    }
}
__global__ void k_scatter_atomic(const int* __restrict__ ei, int* __restrict__ cursor,
                                 int* __restrict__ sorted_src, int E) {
    int base = (blockIdx.x * blockDim.x + threadIdx.x) * 4;
#pragma unroll
    for (int u = 0; u < 4; u++) {
        int e = base + u;
        if (e < E) {
            int p = atomicAdd(&cursor[ei[E + e]], 1);
            sorted_src[p] = ei[e];
        }
    }
}

// fallback-path layer 1 (standalone; unchanged)
__global__ __launch_bounds__(256, 1) void k_node1(
                        const int* __restrict__ offsets, const int* __restrict__ sorted_src,
                        const float* __restrict__ pos,
                        const float* __restrict__ Wl1, const float* __restrict__ bl1,
                        const float* __restrict__ Wr1, const float* __restrict__ Wse1,
                        __half* __restrict__ h1, int N) {
    __shared__ float sWl1[2 * HID], sWr1[2 * HID], sbl1[HID], sWse1[HID * HID];
    __shared__ float sH[32][HID + 4];
    for (int i = threadIdx.x; i < 2 * HID; i += blockDim.x) { sWl1[i] = Wl1[i]; sWr1[i] = Wr1[i]; }
    for (int i = threadIdx.x; i < HID; i += blockDim.x) sbl1[i] = bl1[i];
    for (int i = threadIdx.x; i < HID * HID; i += blockDim.x) sWse1[i] = Wse1[i];
    __syncthreads();

    const int lt = threadIdx.x;
    const int nodeL = lt >> 3;
    const int t = lt & 7;
    const int node = blockIdx.x * 32 + nodeL;
    const bool live = node < N;

    float a0 = 0.f, a1 = 0.f;
    if (live) {
        int beg = offsets[node], end = offsets[node + 1];
        for (int e = beg + t; e < end; e += 8) {
            int s = sorted_src[e];
            a0 += pos[s * 3];
            a1 += pos[s * 3 + 1];
        }
    }
    a0 += __shfl_xor(a0, 1); a1 += __shfl_xor(a1, 1);
    a0 += __shfl_xor(a0, 2); a1 += __shfl_xor(a1, 2);
    a0 += __shfl_xor(a0, 4); a1 += __shfl_xor(a1, 4);

    if (live) {
        float x0 = pos[3 * node], x1 = pos[3 * node + 1];
#pragma unroll
        for (int jj = 0; jj < 4; jj++) {
            int k = t * 4 + jj;
            float v = a0 * sWl1[k] + a1 * sWl1[HID + k] + sbl1[k] + x0 * sWr1[k] + x1 * sWr1[HID + k];
            sH[nodeL][k] = v > 0.f ? v : LEAKY * v;
        }
    }
    __syncthreads();

    if (live) {
        float4 acc = make_float4(0.f, 0.f, 0.f, 0.f);
#pragma unroll 8
        for (int k = 0; k < HID; k++) {
            float hk = sH[nodeL][k];
            float4 w = *(const float4*)&sWse1[k * HID + t * 4];
            acc.x += hk * w.x; acc.y += hk * w.y;
            acc.z += hk * w.z; acc.w += hk * w.w;
        }
        union Pack4 { __half h[4]; float2 v; } p;
        p.h[0] = __float2half(acc.x * SE3NORM);
        p.h[1] = __float2half(acc.y * SE3NORM);
        p.h[2] = __float2half(acc.z * SE3NORM);
        p.h[3] = __float2half(acc.w * SE3NORM);
        *(float2*)&h1[(size_t)node * HID + t * 4] = p.v;
    }
}

// accumulate an 8-byte h1 fragment (4 halves in a float2)
__device__ __forceinline__ void acc_h1frag(float2 r, float4& acc) {
    __half2 p01 = __builtin_bit_cast(__half2, r.x);
    __half2 p23 = __builtin_bit_cast(__half2, r.y);
    acc.x += __low2float(p01); acc.y += __high2float(p01);
    acc.z += __low2float(p23); acc.w += __high2float(p23);
}

// layer 2 + head (round-6/9 verified 74 us; line-fill-concurrency-bound). Untouched.
__global__ __launch_bounds__(512, 1) void k_node2out(
                           const int* __restrict__ offsets, const int* __restrict__ sorted_src,
                           const __half* __restrict__ h1,
                           const float* __restrict__ Wl2, const float* __restrict__ bl2,
                           const float* __restrict__ Wr2, const float* __restrict__ Wse2,
                           const float* __restrict__ W3, const float* __restrict__ b3,
                           const float* __restrict__ W4, const float* __restrict__ b4,
                           const float* __restrict__ alpha_p,
                           float* __restrict__ out, int N) {
    __shared__ float sWl2[HID * HID], sWr2[HID * HID], sWse2[HID * HID], sW3[HID * HID];
    __shared__ float sbl2[HID], sb3[HID], sW4[HID];
    __shared__ float sb4, salpha;
    __shared__ float sA[NPB2][HID + 4], sB[NPB2][HID + 4];
    for (int i = threadIdx.x; i < HID * HID; i += blockDim.x) {
        sWl2[i] = Wl2[i]; sWr2[i] = Wr2[i]; sWse2[i] = Wse2[i]; sW3[i] = W3[i];
    }
    for (int i = threadIdx.x; i < HID; i += blockDim.x) { sbl2[i] = bl2[i]; sb3[i] = b3[i]; sW4[i] = W4[i]; }
    if (threadIdx.x == 0) { sb4 = b4[0]; salpha = alpha_p[0]; }
    __syncthreads();

    const int lt = threadIdx.x;
    const int nodeL = lt >> 3;       // 0..63
    const int t = lt & 7;
    const int node = blockIdx.x * NPB2 + nodeL;
    const bool live = node < N;

    if (live) {
        float2 ro = *(const float2*)&h1[(size_t)node * HID + t * 4];

        int beg = offsets[node], end = offsets[node + 1];
        float4 acc = make_float4(0.f, 0.f, 0.f, 0.f);
        int e = beg;
        for (; e + 8 <= end; e += 8) {
            int s0 = __builtin_nontemporal_load(&sorted_src[e + 0]);
            int s1 = __builtin_nontemporal_load(&sorted_src[e + 1]);
            int s2 = __builtin_nontemporal_load(&sorted_src[e + 2]);
            int s3 = __builtin_nontemporal_load(&sorted_src[e + 3]);
            int s4 = __builtin_nontemporal_load(&sorted_src[e + 4]);
            int s5 = __builtin_nontemporal_load(&sorted_src[e + 5]);
            int s6 = __builtin_nontemporal_load(&sorted_src[e + 6]);
            int s7 = __builtin_nontemporal_load(&sorted_src[e + 7]);
            float2 r0 = *(const float2*)&h1[(size_t)s0 * HID + t * 4];
            float2 r1 = *(const float2*)&h1[(size_t)s1 * HID + t * 4];
            float2 r2 = *(const float2*)&h1[(size_t)s2 * HID + t * 4];
            float2 r3 = *(const float2*)&h1[(size_t)s3 * HID + t * 4];
            float2 r4 = *(const float2*)&h1[(size_t)s4 * HID + t * 4];
            float2 r5 = *(const float2*)&h1[(size_t)s5 * HID + t * 4];
            float2 r6 = *(const float2*)&h1[(size_t)s6 * HID + t * 4];
            float2 r7 = *(const float2*)&h1[(size_t)s7 * HID + t * 4];
            acc_h1frag(r0, acc); acc_h1frag(r1, acc);
            acc_h1frag(r2, acc); acc_h1frag(r3, acc);
            acc_h1frag(r4, acc); acc_h1frag(r5, acc);
            acc_h1frag(r6, acc); acc_h1frag(r7, acc);
        }
        for (; e < end; e++) {
            int s = __builtin_nontemporal_load(&sorted_src[e]);
            float2 r = *(const float2*)&h1[(size_t)s * HID + t * 4];
            acc_h1frag(r, acc);
        }
        __half2 o01 = __builtin_bit_cast(__half2, ro.x);
        __half2 o23 = __builtin_bit_cast(__half2, ro.y);
        float4 own = make_float4(__low2float(o01), __high2float(o01),
                                 __low2float(o23), __high2float(o23));
        *(float4*)&sA[nodeL][t * 4] = acc;
        *(float4*)&sB[nodeL][t * 4] = own;
    }
    __syncthreads();

    float h2r[4];
    if (live) {
        h2r[0] = sbl2[t * 4 + 0]; h2r[1] = sbl2[t * 4 + 1];
        h2r[2] = sbl2[t * 4 + 2]; h2r[3] = sbl2[t * 4 + 3];
#pragma unroll 8
        for (int k = 0; k < HID; k++) {
            float a = sA[nodeL][k];
            float b = sB[nodeL][k];
            float4 wl = *(const float4*)&sWl2[k * HID + t * 4];
            float4 wr = *(const float4*)&sWr2[k * HID + t * 4];
            h2r[0] += a * wl.x + b * wr.x;
            h2r[1] += a * wl.y + b * wr.y;
            h2r[2] += a * wl.z + b * wr.z;
            h2r[3] += a * wl.w + b * wr.w;
        }
#pragma unroll
        for (int jj = 0; jj < 4; jj++) h2r[jj] = h2r[jj] > 0.f ? h2r[jj] : LEAKY * h2r[jj];
    }
    __syncthreads();
    if (live) {
        float4 st = make_float4(h2r[0], h2r[1], h2r[2], h2r[3]);
        *(float4*)&sA[nodeL][t * 4] = st;
    }
    __syncthreads();

    if (live) {
        float4 acc = make_float4(0.f, 0.f, 0.f, 0.f);
#pragma unroll 8
        for (int k = 0; k < HID; k++) {
            float a = sA[nodeL][k];
            float4 w = *(const float4*)&sWse2[k * HID + t * 4];
            acc.x += a * w.x; acc.y += a * w.y;
            acc.z += a * w.z; acc.w += a * w.w;
        }
        float4 own = *(const float4*)&sB[nodeL][t * 4];
        own.x = salpha * own.x + acc.x * SE3NORM;
        own.y = salpha * own.y + acc.y * SE3NORM;
        own.z = salpha * own.z + acc.z * SE3NORM;
        own.w = salpha * own.w + acc.w * SE3NORM;
        *(float4*)&sB[nodeL][t * 4] = own;
    }
    __syncthreads();

    float acc4[4];
    acc4[0] = sb3[t * 4 + 0]; acc4[1] = sb3[t * 4 + 1];
    acc4[2] = sb3[t * 4 + 2]; acc4[3] = sb3[t * 4 + 3];
    if (live) {
#pragma unroll 8
        for (int k = 0; k < HID; k++) {
            float s = sB[nodeL][k];
            float4 w = *(const float4*)&sW3[k * HID + t * 4];
            acc4[0] += s * w.x; acc4[1] += s * w.y;
            acc4[2] += s * w.z; acc4[3] += s * w.w;
        }
    }
    float part = 0.f;
#pragma unroll
    for (int jj = 0; jj < 4; jj++)
        part += (acc4[jj] > 0.f ? acc4[jj] : 0.f) * sW4[t * 4 + jj];
    part += __shfl_xor(part, 1);
    part += __shfl_xor(part, 2);
    part += __shfl_xor(part, 4);
    if (live && t == 0) out[node] = part + sb4;
}

extern "C" void kernel_launch(void* const* d_in, const int* in_sizes, int n_in,
                              void* d_out, int out_size, void* d_ws, size_t ws_size,
                              hipStream_t stream) {
    const float* pos  = (const float*)d_in[0];
    const int*   ei   = (const int*)d_in[1];
    const float* Wl1  = (const float*)d_in[2];
    const float* bl1  = (const float*)d_in[3];
    const float* Wr1  = (const float*)d_in[4];
    const float* Wl2  = (const float*)d_in[5];
    const float* bl2  = (const float*)d_in[6];
    const float* Wr2  = (const float*)d_in[7];
    const float* Wse1 = (const float*)d_in[8];
    const float* Wse2 = (const float*)d_in[9];
    const float* W3   = (const float*)d_in[10];
    const float* b3   = (const float*)d_in[11];
    const float* W4   = (const float*)d_in[12];
    const float* b4   = (const float*)d_in[13];
    const float* alp  = (const float*)d_in[14];
    float* out = (float*)d_out;

    const int N = in_sizes[0] / 3;
    const int E = in_sizes[1] / 2;
    const int blk = 256;
    const size_t h1bytes = (size_t)N * HID * sizeof(__half);

    // ---- two-level bucket sort, no global atomics ----
    const int B1 = (N + NBK - 1) / NBK;
    const int M2 = B1 * GA;
    const int S2 = (M2 + SCAN_TILE - 1) / SCAN_TILE;
    {
        int* bh         = (int*)d_ws;
        int* bsum       = bh + M2;
        int* bucketed   = bsum + 1024;
        int* sorted_src = bucketed + E;
        int* offsets    = sorted_src + E;
        uintptr_t hp = ((uintptr_t)(offsets + N + 1) + 15) & ~(uintptr_t)15;
        size_t need = (hp - (uintptr_t)d_ws) + h1bytes;
        const int chunk = (E + GA - 1) / GA;
        if (need <= ws_size && S2 <= 1024 && B1 <= 1024 && chunk <= CHCAP) {
            __half* h1 = (__half*)hp;
            const size_t ldsB = (size_t)B1 * sizeof(int);
            const size_t ldsB2 = (size_t)(3 * B1) * sizeof(int) + (size_t)CHCAP * sizeof(unsigned short);
            k_bhist<<<GA, 256, ldsB, stream>>>(ei, bh, E, B1, chunk);
            k_scan1<<<S2, 256, 0, stream>>>(bh, bsum, M2);
            k_scan2<<<1, 256, 0, stream>>>(bsum, S2);
            k_bscatter2<<<GA, 256, ldsB2, stream>>>(ei, bh, bsum, bucketed, E, B1, chunk);
            k_bsortn1<<<B1, 512, 0, stream>>>(bh, bsum, bucketed, pos,
                                              Wl1, bl1, Wr1, Wse1,
                                              sorted_src, offsets, h1, E, N, B1);
            k_node2out<<<(N + NPB2 - 1) / NPB2, 512, 0, stream>>>(offsets, sorted_src, h1,
                                                          Wl2, bl2, Wr2, Wse2,
                                                          W3, b3, W4, b4, alp, out, N);
            return;
        }
    }

    // ---- fallback: R4 global-atomic CSR build ----
    const int M = N + 1;
    const int B = (M + SCAN_TILE - 1) / SCAN_TILE;
    int* hist       = (int*)d_ws;
    int* offsets    = hist + M;   // unused (in-place scan) but keeps layout roomy
    int* bsum       = offsets + M;
    int* sorted_src = bsum + 1024;
    int* aux        = sorted_src + E;
    uintptr_t hpA = ((uintptr_t)(aux + E) + 15) & ~(uintptr_t)15;
    uintptr_t hpB = ((uintptr_t)(aux + N) + 15) & ~(uintptr_t)15;
    size_t needA = (hpA - (uintptr_t)d_ws) + h1bytes;
    const bool useRank = (needA <= ws_size);
    __half* h1 = (__half*)(useRank ? hpA : hpB);

    hipMemsetAsync(hist, 0, (size_t)M * sizeof(int), stream);
    const int egrid4 = (E / 4 + blk) / blk;
    if (useRank) {
        k_hist_rank<<<egrid4, blk, 0, stream>>>(ei, hist, aux, E);
    } else {
        k_hist<<<egrid4, blk, 0, stream>>>(ei, hist, E);
    }
    k_scan1<<<B, 256, 0, stream>>>(hist, bsum, M);
    k_scan2<<<1, 256, 0, stream>>>(bsum, B);
    k_scan3<<<(M + blk - 1) / blk, blk, 0, stream>>>(hist, bsum, useRank ? nullptr : aux, M, N);
    int* offs = hist;
    if (useRank) {
        k_scatter_rank<<<egrid4, blk, 0, stream>>>(ei, offs, aux, sorted_src, E);
    } else {
        k_scatter_atomic<<<egrid4, blk, 0, stream>>>(ei, aux, sorted_src, E);
    }
    k_node1<<<(N + 31) / 32, 256, 0, stream>>>(offs, sorted_src, pos, Wl1, bl1, Wr1, Wse1, h1, N);
    k_node2out<<<(N + NPB2 - 1) / NPB2, 512, 0, stream>>>(offs, sorted_src, h1, Wl2, bl2, Wr2, Wse2,
                                                  W3, b3, W4, b4, alp, out, N);
}